// Round 9
// baseline (554.929 us; speedup 1.0000x reference)
//
#include <hip/hip_runtime.h>

// Problem constants
#define DIMD   256
#define NTOK   16384
#define NCODE  8192
#define NELEM  (NTOK * DIMD)

// fp32 project-GEMM tiling
#define BM 128
#define BK 128
#define BD 32
#define PAD 4
#define LDS_STRIDE (BM + PAD)

// streaming distance kernel
#define SPLITS_B 2
#define NTILES (NTOK / 64)                       // 256
#define CODES_PER_WAVE (NCODE / SPLITS_B / 4)    // 1024
#define NGROUPS (CODES_PER_WAVE / 16)            // 64
#define NCHUNK (NCODE / 64)                      // 128 chunk-mins per token
#define MARGIN 0.5f                              // > two-sided worst-case bf16 distance error

typedef float floatx4 __attribute__((ext_vector_type(4)));
typedef short short8  __attribute__((ext_vector_type(8)));

__device__ __forceinline__ unsigned short f2bf(float f) {
    unsigned u = __float_as_uint(f);
    unsigned r = (u + 0x7FFFu + ((u >> 16) & 1u)) >> 16;
    return (unsigned short)r;
}

__device__ __forceinline__ unsigned long long shfl_xor_u64(unsigned long long v, int off) {
    unsigned lo = (unsigned)v, hi = (unsigned)(v >> 32);
    lo = __shfl_xor(lo, off); hi = __shfl_xor(hi, off);
    return ((unsigned long long)hi << 32) | lo;
}

// -------------------------------------------------------------------------
// Kernel 1: codebook projection C = E @ W^T + b (fp32) + bf16 copy Cb.
// -------------------------------------------------------------------------
__global__ __launch_bounds__(256, 3)
void project_kernel(const float* __restrict__ E, const float* __restrict__ W,
                    const float* __restrict__ bias, float* __restrict__ C,
                    unsigned short* __restrict__ Cb)
{
    __shared__ float smem[2 * BD * LDS_STRIDE];
    float* As = smem;
    float* Bs = smem + BD * LDS_STRIDE;

    const int tid = threadIdx.x;
    const int tx  = tid & 15;
    const int ty  = tid >> 4;
    const int m0  = blockIdx.x * BM;
    const int j0  = blockIdx.y * BK;

    const int srow = tid >> 3;
    const int scol = (tid & 7) * 4;

    float acc[8][8];
#pragma unroll
    for (int i = 0; i < 8; ++i)
#pragma unroll
        for (int j = 0; j < 8; ++j) acc[i][j] = 0.f;

    for (int dc = 0; dc < DIMD / BD; ++dc) {
        const int d0 = dc * BD;
        __syncthreads();
#pragma unroll
        for (int rr = 0; rr < 4; ++rr) {
            const int r = srow + rr * 32;
            float4 av = *(const float4*)&E[(size_t)(m0 + r) * DIMD + d0 + scol];
            As[(scol + 0) * LDS_STRIDE + r] = av.x;
            As[(scol + 1) * LDS_STRIDE + r] = av.y;
            As[(scol + 2) * LDS_STRIDE + r] = av.z;
            As[(scol + 3) * LDS_STRIDE + r] = av.w;
            float4 bv = *(const float4*)&W[(size_t)(j0 + r) * DIMD + d0 + scol];
            Bs[(scol + 0) * LDS_STRIDE + r] = bv.x;
            Bs[(scol + 1) * LDS_STRIDE + r] = bv.y;
            Bs[(scol + 2) * LDS_STRIDE + r] = bv.z;
            Bs[(scol + 3) * LDS_STRIDE + r] = bv.w;
        }
        __syncthreads();
#pragma unroll 4
        for (int d = 0; d < BD; ++d) {
            float4 a0 = *(float4*)&As[d * LDS_STRIDE + ty * 4];
            float4 a1 = *(float4*)&As[d * LDS_STRIDE + 64 + ty * 4];
            float4 b0 = *(float4*)&Bs[d * LDS_STRIDE + tx * 4];
            float4 b1 = *(float4*)&Bs[d * LDS_STRIDE + 64 + tx * 4];
            float a[8] = {a0.x, a0.y, a0.z, a0.w, a1.x, a1.y, a1.z, a1.w};
            float b[8] = {b0.x, b0.y, b0.z, b0.w, b1.x, b1.y, b1.z, b1.w};
#pragma unroll
            for (int i = 0; i < 8; ++i)
#pragma unroll
                for (int j = 0; j < 8; ++j) acc[i][j] = fmaf(a[i], b[j], acc[i][j]);
        }
    }

    float4 bja = *(const float4*)&bias[j0 + tx * 4];
    float4 bjb = *(const float4*)&bias[j0 + 64 + tx * 4];
#pragma unroll
    for (int i = 0; i < 8; ++i) {
        const int mloc = (i < 4) ? (ty * 4 + i) : (64 + ty * 4 + (i - 4));
        const size_t row = (size_t)(m0 + mloc) * DIMD;
        float o[8] = {acc[i][0] + bja.x, acc[i][1] + bja.y, acc[i][2] + bja.z, acc[i][3] + bja.w,
                      acc[i][4] + bjb.x, acc[i][5] + bjb.y, acc[i][6] + bjb.z, acc[i][7] + bjb.w};
        *(float4*)&C[row + j0 + tx * 4]      = *(float4*)&o[0];
        *(float4*)&C[row + j0 + 64 + tx * 4] = *(float4*)&o[4];
        ushort4 h0 = {f2bf(o[0]), f2bf(o[1]), f2bf(o[2]), f2bf(o[3])};
        ushort4 h1 = {f2bf(o[4]), f2bf(o[5]), f2bf(o[6]), f2bf(o[7])};
        *(ushort4*)&Cb[row + j0 + tx * 4]      = h0;
        *(ushort4*)&Cb[row + j0 + 64 + tx * 4] = h1;
    }
}

// -------------------------------------------------------------------------
// Kernel 2a: X -> xnorm + bf16 Xb.  Kernel 2b: cnorm from fp32 C.
// -------------------------------------------------------------------------
__global__ void convx_kernel(const float* __restrict__ X, float* __restrict__ xnorm,
                             unsigned short* __restrict__ Xb)
{
    const int wave = threadIdx.x >> 6;
    const int lane = threadIdx.x & 63;
    const int row  = blockIdx.x * 4 + wave;
    float4 v = *(const float4*)&X[(size_t)row * DIMD + lane * 4];
    ushort4 h = {f2bf(v.x), f2bf(v.y), f2bf(v.z), f2bf(v.w)};
    *(ushort4*)&Xb[(size_t)row * DIMD + lane * 4] = h;
    float s = v.x * v.x + v.y * v.y + v.z * v.z + v.w * v.w;
#pragma unroll
    for (int off = 1; off < 64; off <<= 1) s += __shfl_xor(s, off);
    if (lane == 0) xnorm[row] = s;
}

__global__ void cnorm_kernel(const float* __restrict__ A, float* __restrict__ out)
{
    const int wave = threadIdx.x >> 6;
    const int lane = threadIdx.x & 63;
    const int row  = blockIdx.x * 4 + wave;
    float4 v = *(const float4*)&A[(size_t)row * DIMD + lane * 4];
    float s = v.x * v.x + v.y * v.y + v.z * v.z + v.w * v.w;
#pragma unroll
    for (int off = 1; off < 64; off <<= 1) s += __shfl_xor(s, off);
    if (lane == 0) out[row] = s;
}

// -------------------------------------------------------------------------
// Kernel 3: single streaming distance GEMM producing a compressed min-map.
// Per group (16 codes): 16 fma + 16 fmin. Every 4 groups (= 1 chunk of 64
// codes): 16-lane butterfly + 16 scattered dword stores (4 active lanes)
// -> chunkmin[token][chunk] = min bf16-distance (cnorm - 2*dot; xnorm
// dropped as a per-token shift). Grid (256 tiles, 2 splits).
// -------------------------------------------------------------------------
__global__ __launch_bounds__(256, 2)
void dist_minmap_kernel(const unsigned short* __restrict__ Xb,
                        const unsigned short* __restrict__ Cb,
                        const float* __restrict__ cnorm,
                        float* __restrict__ chunkmin)
{
    const int tid  = threadIdx.x;
    const int lane = tid & 63;
    const int wv   = tid >> 6;
    const int l15  = lane & 15;
    const int quad = lane >> 4;
    const int tok0 = blockIdx.x * 64;
    const int cbase = blockIdx.y * (NCODE / SPLITS_B) + wv * CODES_PER_WAVE;
    const int chunk0 = cbase >> 6;           // 16 chunks per wave

    // A fragments: 64 tokens x 256 k, register-resident
    short8 a[4][8];
#pragma unroll
    for (int i = 0; i < 4; ++i) {
        const unsigned short* ap = Xb + (size_t)(tok0 + i * 16 + l15) * DIMD + quad * 8;
#pragma unroll
        for (int ks = 0; ks < 8; ++ks)
            a[i][ks] = *(const short8*)(ap + ks * 32);
    }

    float runc[16];
#pragma unroll
    for (int s = 0; s < 16; ++s) runc[s] = 3.4e38f;

    const unsigned short* bp0 = Cb + (size_t)(cbase + l15) * DIMD + quad * 8;
    short8 breg[2][8];
    float  cnr[2];
#pragma unroll
    for (int ks = 0; ks < 8; ++ks) breg[0][ks] = *(const short8*)(bp0 + ks * 32);
    cnr[0] = cnorm[cbase + l15];

    auto body = [&](int g, short8 (&bc)[8], short8 (&bn)[8],
                    float cnc, float& cnn, bool flush) {
        if (g + 1 < NGROUPS) {
            const unsigned short* bpn = bp0 + (size_t)(g + 1) * (16 * DIMD);
#pragma unroll
            for (int ks = 0; ks < 8; ++ks) bn[ks] = *(const short8*)(bpn + ks * 32);
            cnn = cnorm[cbase + (g + 1) * 16 + l15];
        }
        floatx4 acc[4];
#pragma unroll
        for (int i = 0; i < 4; ++i) acc[i] = (floatx4){0.f, 0.f, 0.f, 0.f};
#pragma unroll
        for (int ks = 0; ks < 8; ++ks)
#pragma unroll
            for (int i = 0; i < 4; ++i)
                acc[i] = __builtin_amdgcn_mfma_f32_16x16x32_bf16(a[i][ks], bc[ks], acc[i], 0, 0, 0);
#pragma unroll
        for (int i = 0; i < 4; ++i)
#pragma unroll
            for (int r = 0; r < 4; ++r)
                runc[i * 4 + r] = fminf(runc[i * 4 + r], fmaf(-2.f, acc[i][r], cnc));

        if (flush) {
            // chunk complete: butterfly over the 16 code-lanes, store, reset
#pragma unroll
            for (int s = 0; s < 16; ++s) {
                float m = runc[s];
#pragma unroll
                for (int off = 1; off < 16; off <<= 1) m = fminf(m, __shfl_xor(m, off));
                runc[s] = m;
            }
            const int c = chunk0 + (g >> 2);
            if (l15 == 0) {
#pragma unroll
                for (int i = 0; i < 4; ++i)
#pragma unroll
                    for (int r = 0; r < 4; ++r)
                        chunkmin[(size_t)(tok0 + i * 16 + quad * 4 + r) * NCHUNK + c] =
                            runc[i * 4 + r];
            }
#pragma unroll
            for (int s = 0; s < 16; ++s) runc[s] = 3.4e38f;
        }
    };

    for (int gg = 0; gg < NGROUPS; gg += 4) {
        body(gg,     breg[0], breg[1], cnr[0], cnr[1], false);
        body(gg + 1, breg[1], breg[0], cnr[1], cnr[0], false);
        body(gg + 2, breg[0], breg[1], cnr[0], cnr[1], false);
        body(gg + 3, breg[1], breg[0], cnr[1], cnr[0], true);
    }
}

// -------------------------------------------------------------------------
// Kernel 4: per-token select + exact rescore + output + loss. One wave per
// 4 tokens. Reads the 128 chunk-mins, thresholds at min+MARGIN, computes
// exact fp32 distances only for hit chunks (~1-2 per token), packed
// (d_bits<<32|code) min -> lowest-index tie-break like np.argmin, then
// gathers the winner row, writes zq + index, accumulates loss per block.
// -------------------------------------------------------------------------
__global__ __launch_bounds__(256)
void select_finalize_kernel(const float* __restrict__ X, const float* __restrict__ C,
                            const float* __restrict__ xnorm, const float* __restrict__ cnorm,
                            const float* __restrict__ chunkmin,
                            float* __restrict__ out, float* __restrict__ partial)
{
    __shared__ float part[4];
    const int lane = threadIdx.x & 63;
    const int wv   = threadIdx.x >> 6;
    const int g16  = lane & 15;
    const int sub  = lane >> 4;

    float lossw = 0.f;

    for (int it = 0; it < 4; ++it) {
        const int t = blockIdx.x * 16 + wv * 4 + it;

        // threshold from the chunk-min map
        float2 cm = *(const float2*)&chunkmin[(size_t)t * NCHUNK + lane * 2];
        float m = fminf(cm.x, cm.y);
#pragma unroll
        for (int off = 1; off < 64; off <<= 1) m = fminf(m, __shfl_xor(m, off));
        const float thr = m + MARGIN;
        const float xn = xnorm[t];

        unsigned long long best = ~0ull;
        unsigned long long m0 = __ballot(cm.x < thr);
        unsigned long long m1 = __ballot(cm.y < thr);

        while (m0 | m1) {
            int chunk;
            if (m0) { int l = __ffsll(m0) - 1; m0 &= m0 - 1; chunk = l * 2; }
            else    { int l = __ffsll(m1) - 1; m1 &= m1 - 1; chunk = l * 2 + 1; }
            // 64 codes: 16 passes x 4 codes (16-lane-group dot products)
            for (int pass = 0; pass < 16; ++pass) {
                const int code = chunk * 64 + pass * 4 + sub;
                const float* xr = &X[(size_t)t * DIMD];
                const float* cr = &C[(size_t)code * DIMD];
                float dot = 0.f;
#pragma unroll
                for (int r = 0; r < 4; ++r) {
                    float4 x4 = *(const float4*)&xr[r * 64 + g16 * 4];
                    float4 c4 = *(const float4*)&cr[r * 64 + g16 * 4];
                    dot = fmaf(x4.x, c4.x, dot);
                    dot = fmaf(x4.y, c4.y, dot);
                    dot = fmaf(x4.z, c4.z, dot);
                    dot = fmaf(x4.w, c4.w, dot);
                }
#pragma unroll
                for (int d = 1; d < 16; d <<= 1) dot += __shfl_xor(dot, d);
                if (g16 == 0) {
                    const float dd = xn + cnorm[code] - 2.f * dot;
                    const unsigned long long p =
                        ((unsigned long long)__float_as_uint(dd) << 32) | (unsigned)code;
                    if (p < best) best = p;
                }
            }
        }
#pragma unroll
        for (int off = 1; off < 64; off <<= 1) {
            unsigned long long o = shfl_xor_u64(best, off);
            if (o < best) best = o;
        }
        const unsigned code = (unsigned)(best & 0xFFFFFFFFull);

        // output: zq = x + (c - x), loss partial, index
        float4 c4 = *(const float4*)&C[(size_t)code * DIMD + lane * 4];
        float4 x4 = *(const float4*)&X[(size_t)t * DIMD + lane * 4];
        float4 w  = {c4.x - x4.x, c4.y - x4.y, c4.z - x4.z, c4.w - x4.w};
        float ssq = w.x * w.x + w.y * w.y + w.z * w.z + w.w * w.w;
        float4 zq = {x4.x + w.x, x4.y + w.y, x4.z + w.z, x4.w + w.w};
        *(float4*)&out[(size_t)t * DIMD + lane * 4] = zq;
#pragma unroll
        for (int off = 1; off < 64; off <<= 1) ssq += __shfl_xor(ssq, off);
        lossw += ssq;
        if (lane == 0) out[NELEM + 1 + t] = (float)code;
    }

    if (lane == 0) part[wv] = lossw;
    __syncthreads();
    if (threadIdx.x == 0)
        partial[blockIdx.x] = part[0] + part[1] + part[2] + part[3];
}

// -------------------------------------------------------------------------
// Kernel 5: reduce the 1024 per-block loss partials -> out[NELEM].
// -------------------------------------------------------------------------
__global__ void loss_reduce_kernel(const float* __restrict__ partial, float* __restrict__ out)
{
    __shared__ float p[4];
    float s = 0.f;
    for (int i = threadIdx.x; i < 1024; i += 256) s += partial[i];
#pragma unroll
    for (int off = 1; off < 64; off <<= 1) s += __shfl_xor(s, off);
    if ((threadIdx.x & 63) == 0) p[threadIdx.x >> 6] = s;
    __syncthreads();
    if (threadIdx.x == 0)
        out[NELEM] = (p[0] + p[1] + p[2] + p[3]) * (1.25f / (float)NELEM);
}

// -------------------------------------------------------------------------
extern "C" void kernel_launch(void* const* d_in, const int* in_sizes, int n_in,
                              void* d_out, int out_size, void* d_ws, size_t ws_size,
                              hipStream_t stream)
{
    const float* X = (const float*)d_in[0];
    const float* E = (const float*)d_in[1];
    const float* W = (const float*)d_in[2];
    const float* b = (const float*)d_in[3];
    float* out = (float*)d_out;

    char* w = (char*)d_ws;
    float* C            = (float*)w;           w += (size_t)NCODE * DIMD * 4;
    unsigned short* Xb  = (unsigned short*)w;  w += (size_t)NTOK * DIMD * 2;
    unsigned short* Cb  = (unsigned short*)w;  w += (size_t)NCODE * DIMD * 2;
    float* xnorm        = (float*)w;           w += (size_t)NTOK * 4;
    float* cnorm        = (float*)w;           w += (size_t)NCODE * 4;
    float* chunkmin     = (float*)w;           w += (size_t)NTOK * NCHUNK * 4;
    float* partial      = (float*)w;           w += 1024 * 4;

    project_kernel<<<dim3(NCODE / BM, DIMD / BK), 256, 0, stream>>>(E, W, b, C, Cb);
    convx_kernel<<<NTOK / 4, 256, 0, stream>>>(X, xnorm, Xb);
    cnorm_kernel<<<NCODE / 4, 256, 0, stream>>>(C, cnorm);
    dist_minmap_kernel<<<dim3(NTILES, SPLITS_B), 256, 0, stream>>>(Xb, Cb, cnorm, chunkmin);
    select_finalize_kernel<<<NTOK / 16, 256, 0, stream>>>(X, C, xnorm, cnorm, chunkmin, out, partial);
    loss_reduce_kernel<<<1, 256, 0, stream>>>(partial, out);
}

// Round 10
// 328.429 us; speedup vs baseline: 1.6896x; 1.6896x over previous
//
#include <hip/hip_runtime.h>

// Problem constants
#define DIMD   256
#define NTOK   16384
#define NCODE  8192
#define NELEM  (NTOK * DIMD)

// fp32 project-GEMM tiling
#define BM 128
#define BK 128
#define BD 32
#define PAD 4
#define LDS_STRIDE (BM + PAD)

// streaming distance kernel
#define SPLITS_B 2                    // grid.y code splits
#define CODES_PER_WAVE (NCODE / SPLITS_B / 4)   // 1024
#define NGROUPS (CODES_PER_WAVE / 16)           // 64
#define MARGIN 0.5f                   // > two-sided worst-case bf16 distance error
#define LDSCAP 6144                   // raw per-block candidate entries
#define FCAP   2048                   // filtered entries

typedef float floatx4 __attribute__((ext_vector_type(4)));
typedef short short8  __attribute__((ext_vector_type(8)));

__device__ __forceinline__ unsigned short f2bf(float f) {
    unsigned u = __float_as_uint(f);
    unsigned r = (u + 0x7FFFu + ((u >> 16) & 1u)) >> 16;
    return (unsigned short)r;
}

// fragment-major Cb index for element (row=code, col=k):
// block (row/16, col/32) of 512 elems; within: lane=(colsub/8)*16+(row%16), elem=col%8
__device__ __forceinline__ size_t cb2_idx(int row, int col) {
    return ((size_t)((row >> 4) * 8 + (col >> 5))) * 512
         + (size_t)((((col >> 3) & 3) * 16 + (row & 15)) * 8 + (col & 7));
}

// -------------------------------------------------------------------------
// Kernel 1: codebook projection C = E @ W^T + b (fp32) + fragment-major
// bf16 copy Cb2 (so the distance GEMM's B-loads are contiguous 1KB/instr).
// -------------------------------------------------------------------------
__global__ __launch_bounds__(256, 3)
void project_kernel(const float* __restrict__ E, const float* __restrict__ W,
                    const float* __restrict__ bias, float* __restrict__ C,
                    unsigned short* __restrict__ Cb2)
{
    __shared__ float smem[2 * BD * LDS_STRIDE];
    float* As = smem;
    float* Bs = smem + BD * LDS_STRIDE;

    const int tid = threadIdx.x;
    const int tx  = tid & 15;
    const int ty  = tid >> 4;
    const int m0  = blockIdx.x * BM;
    const int j0  = blockIdx.y * BK;

    const int srow = tid >> 3;
    const int scol = (tid & 7) * 4;

    float acc[8][8];
#pragma unroll
    for (int i = 0; i < 8; ++i)
#pragma unroll
        for (int j = 0; j < 8; ++j) acc[i][j] = 0.f;

    for (int dc = 0; dc < DIMD / BD; ++dc) {
        const int d0 = dc * BD;
        __syncthreads();
#pragma unroll
        for (int rr = 0; rr < 4; ++rr) {
            const int r = srow + rr * 32;
            float4 av = *(const float4*)&E[(size_t)(m0 + r) * DIMD + d0 + scol];
            As[(scol + 0) * LDS_STRIDE + r] = av.x;
            As[(scol + 1) * LDS_STRIDE + r] = av.y;
            As[(scol + 2) * LDS_STRIDE + r] = av.z;
            As[(scol + 3) * LDS_STRIDE + r] = av.w;
            float4 bv = *(const float4*)&W[(size_t)(j0 + r) * DIMD + d0 + scol];
            Bs[(scol + 0) * LDS_STRIDE + r] = bv.x;
            Bs[(scol + 1) * LDS_STRIDE + r] = bv.y;
            Bs[(scol + 2) * LDS_STRIDE + r] = bv.z;
            Bs[(scol + 3) * LDS_STRIDE + r] = bv.w;
        }
        __syncthreads();
#pragma unroll 4
        for (int d = 0; d < BD; ++d) {
            float4 a0 = *(float4*)&As[d * LDS_STRIDE + ty * 4];
            float4 a1 = *(float4*)&As[d * LDS_STRIDE + 64 + ty * 4];
            float4 b0 = *(float4*)&Bs[d * LDS_STRIDE + tx * 4];
            float4 b1 = *(float4*)&Bs[d * LDS_STRIDE + 64 + tx * 4];
            float a[8] = {a0.x, a0.y, a0.z, a0.w, a1.x, a1.y, a1.z, a1.w};
            float b[8] = {b0.x, b0.y, b0.z, b0.w, b1.x, b1.y, b1.z, b1.w};
#pragma unroll
            for (int i = 0; i < 8; ++i)
#pragma unroll
                for (int j = 0; j < 8; ++j) acc[i][j] = fmaf(a[i], b[j], acc[i][j]);
        }
    }

    float4 bja = *(const float4*)&bias[j0 + tx * 4];
    float4 bjb = *(const float4*)&bias[j0 + 64 + tx * 4];
#pragma unroll
    for (int i = 0; i < 8; ++i) {
        const int mloc = (i < 4) ? (ty * 4 + i) : (64 + ty * 4 + (i - 4));
        const int row  = m0 + mloc;
        const size_t rbase = (size_t)row * DIMD;
        float o[8] = {acc[i][0] + bja.x, acc[i][1] + bja.y, acc[i][2] + bja.z, acc[i][3] + bja.w,
                      acc[i][4] + bjb.x, acc[i][5] + bjb.y, acc[i][6] + bjb.z, acc[i][7] + bjb.w};
        *(float4*)&C[rbase + j0 + tx * 4]      = *(float4*)&o[0];
        *(float4*)&C[rbase + j0 + 64 + tx * 4] = *(float4*)&o[4];
        ushort4 h0 = {f2bf(o[0]), f2bf(o[1]), f2bf(o[2]), f2bf(o[3])};
        ushort4 h1 = {f2bf(o[4]), f2bf(o[5]), f2bf(o[6]), f2bf(o[7])};
        *(ushort4*)&Cb2[cb2_idx(row, j0 + tx * 4)]      = h0;
        *(ushort4*)&Cb2[cb2_idx(row, j0 + 64 + tx * 4)] = h1;
    }
}

// -------------------------------------------------------------------------
// Kernel 2a: X -> xnorm + bf16 Xb (row-major; A-loads are once per wave).
// -------------------------------------------------------------------------
__global__ void convx_kernel(const float* __restrict__ X, float* __restrict__ xnorm,
                             unsigned short* __restrict__ Xb)
{
    const int wave = threadIdx.x >> 6;
    const int lane = threadIdx.x & 63;
    const int row  = blockIdx.x * 4 + wave;
    float4 v = *(const float4*)&X[(size_t)row * DIMD + lane * 4];
    ushort4 h = {f2bf(v.x), f2bf(v.y), f2bf(v.z), f2bf(v.w)};
    *(ushort4*)&Xb[(size_t)row * DIMD + lane * 4] = h;
    float s = v.x * v.x + v.y * v.y + v.z * v.z + v.w * v.w;
#pragma unroll
    for (int off = 1; off < 64; off <<= 1) s += __shfl_xor(s, off);
    if (lane == 0) xnorm[row] = s;
}

__global__ void cnorm_kernel(const float* __restrict__ A, float* __restrict__ out)
{
    const int wave = threadIdx.x >> 6;
    const int lane = threadIdx.x & 63;
    const int row  = blockIdx.x * 4 + wave;
    float4 v = *(const float4*)&A[(size_t)row * DIMD + lane * 4];
    float s = v.x * v.x + v.y * v.y + v.z * v.z + v.w * v.w;
#pragma unroll
    for (int off = 1; off < 64; off <<= 1) s += __shfl_xor(s, off);
    if (lane == 0) out[row] = s;
}

// -------------------------------------------------------------------------
// Kernel 3: round-6 barrier-free streaming distance + argmin-candidate
// kernel, with ONE change: B reads from fragment-major Cb2 — every load is
// a contiguous 1KB wave-load (lane*16B), not 16 scattered cachelines.
// -------------------------------------------------------------------------
__global__ __launch_bounds__(256, 2)
void dist_stream_kernel(const unsigned short* __restrict__ Xb,
                        const unsigned short* __restrict__ Cb2,
                        const float* __restrict__ cnorm,
                        unsigned* __restrict__ list, unsigned* __restrict__ count,
                        unsigned cap)
{
    __shared__ unsigned cbuf[LDSCAP];   // 24 KB
    __shared__ float    cval[LDSCAP];   // 24 KB
    __shared__ unsigned fbuf[FCAP];     // 8 KB
    __shared__ float    wmin[4][64];
    __shared__ float    tokthr[64];
    __shared__ unsigned lcnt, fcnt, gbase;

    const int tid  = threadIdx.x;
    const int lane = tid & 63;
    const int wv   = tid >> 6;
    const int l15  = lane & 15;
    const int quad = lane >> 4;
    const int tok0 = blockIdx.x * 64;
    const int cbase = blockIdx.y * (NCODE / SPLITS_B) + wv * CODES_PER_WAVE;

    if (tid == 0) { lcnt = 0; fcnt = 0; }
    __syncthreads();

    // A fragments: 64 tokens x 256 k, register-resident (128 regs)
    short8 a[4][8];
#pragma unroll
    for (int i = 0; i < 4; ++i) {
        const unsigned short* ap = Xb + (size_t)(tok0 + i * 16 + l15) * DIMD + quad * 8;
#pragma unroll
        for (int ks = 0; ks < 8; ++ks)
            a[i][ks] = *(const short8*)(ap + ks * 32);
    }

    float runv[16];
#pragma unroll
    for (int s = 0; s < 16; ++s) runv[s] = 3.4e38f;

    // fragment-major base: block (g,ks) = 512 elems; this wave starts at
    // group cbase/16; each lane reads its own 16B at lane*8.
    const unsigned short* bp0 = Cb2 + (size_t)cbase * DIMD + lane * 8;

    short8 breg[2][8];
    float  cnr[2];
#pragma unroll
    for (int ks = 0; ks < 8; ++ks) breg[0][ks] = *(const short8*)(bp0 + ks * 512);
    cnr[0] = cnorm[cbase + l15];

    auto group_body = [&](int g, short8 (&bc)[8], short8 (&bn)[8],
                          float cnc, float& cnn) {
        const int code0 = cbase + g * 16;
        if (g + 1 < NGROUPS) {
            const unsigned short* bpn = bp0 + (size_t)(g + 1) * 4096;
#pragma unroll
            for (int ks = 0; ks < 8; ++ks) bn[ks] = *(const short8*)(bpn + ks * 512);
            cnn = cnorm[code0 + 16 + l15];
        }

        floatx4 acc[4];
#pragma unroll
        for (int i = 0; i < 4; ++i) acc[i] = (floatx4){0.f, 0.f, 0.f, 0.f};
#pragma unroll
        for (int ks = 0; ks < 8; ++ks)
#pragma unroll
            for (int i = 0; i < 4; ++i)
                acc[i] = __builtin_amdgcn_mfma_f32_16x16x32_bf16(a[i][ks], bc[ks], acc[i], 0, 0, 0);

        if (g != 0 && (g & 7) == 0) {
#pragma unroll
            for (int s = 0; s < 16; ++s) {
                float m = runv[s];
#pragma unroll
                for (int off = 1; off < 16; off <<= 1) m = fminf(m, __shfl_xor(m, off));
                runv[s] = m;
            }
        }

        float slack = 3.4e38f;
#pragma unroll
        for (int i = 0; i < 4; ++i)
#pragma unroll
            for (int r = 0; r < 4; ++r) {
                const int s = i * 4 + r;
                const float dd = fmaf(-2.f, acc[i][r], cnc);
                runv[s] = fminf(runv[s], dd);
                slack = fminf(slack, dd - runv[s]);
            }

        if (g == 0) {
#pragma unroll
            for (int s = 0; s < 16; ++s) {
                float m = runv[s];
#pragma unroll
                for (int off = 1; off < 16; off <<= 1) m = fminf(m, __shfl_xor(m, off));
                runv[s] = m;
            }
            slack = 3.4e38f;
#pragma unroll
            for (int i = 0; i < 4; ++i)
#pragma unroll
                for (int r = 0; r < 4; ++r) {
                    const float dd = fmaf(-2.f, acc[i][r], cnc);
                    slack = fminf(slack, dd - runv[i * 4 + r]);
                }
        }

        if (__any(slack < MARGIN)) {
#pragma unroll
            for (int i = 0; i < 4; ++i)
#pragma unroll
                for (int r = 0; r < 4; ++r) {
                    const int s = i * 4 + r;
                    const float dd = fmaf(-2.f, acc[i][r], cnc);
                    const bool c = (dd - runv[s]) < MARGIN;
                    const unsigned long long m = __ballot(c);
                    if (m == 0ull) continue;
                    if (c) {
                        const int leader = __ffsll(m) - 1;
                        const unsigned prefix =
                            (unsigned)__popcll(m & ((1ull << lane) - 1ull));
                        unsigned base = 0;
                        if (lane == leader)
                            base = atomicAdd(&lcnt, (unsigned)__popcll(m));
                        base = __shfl(base, leader);
                        const unsigned pos = base + prefix;
                        const unsigned token = tok0 + i * 16 + quad * 4 + r;
                        const unsigned entry = (token << 13) | (unsigned)(code0 + l15);
                        if (pos < LDSCAP) { cbuf[pos] = entry; cval[pos] = dd; }
                        else { unsigned gp = atomicAdd(count, 1u); if (gp < cap) list[gp] = entry; }
                    }
                }
        }
    };

    for (int gg = 0; gg < NGROUPS; gg += 2) {
        group_body(gg,     breg[0], breg[1], cnr[0], cnr[1]);
        group_body(gg + 1, breg[1], breg[0], cnr[1], cnr[0]);
    }

#pragma unroll
    for (int s = 0; s < 16; ++s) {
        float m = runv[s];
#pragma unroll
        for (int off = 1; off < 16; off <<= 1) m = fminf(m, __shfl_xor(m, off));
        runv[s] = m;
    }
    if (l15 == 0) {
#pragma unroll
        for (int i = 0; i < 4; ++i)
#pragma unroll
            for (int r = 0; r < 4; ++r)
                wmin[wv][i * 16 + quad * 4 + r] = runv[i * 4 + r];
    }
    __syncthreads();
    if (tid < 64)
        tokthr[tid] = fminf(fminf(wmin[0][tid], wmin[1][tid]),
                            fminf(wmin[2][tid], wmin[3][tid])) + MARGIN;
    __syncthreads();

    const unsigned nn = (lcnt < LDSCAP) ? lcnt : LDSCAP;
    for (unsigned i = tid; i < nn; i += 256) {
        const unsigned e = cbuf[i];
        const unsigned tl = (e >> 13) - (unsigned)tok0;
        if (cval[i] < tokthr[tl]) {
            unsigned p = atomicAdd(&fcnt, 1u);
            if (p < FCAP) fbuf[p] = e;
            else { unsigned gp = atomicAdd(count, 1u); if (gp < cap) list[gp] = e; }
        }
    }
    __syncthreads();

    const unsigned fn = (fcnt < FCAP) ? fcnt : FCAP;
    if (tid == 0) gbase = atomicAdd(count, fn);
    __syncthreads();
    const unsigned gb = gbase;
    for (unsigned i = tid; i < fn; i += 256) {
        const unsigned p = gb + i;
        if (p < cap) list[p] = fbuf[i];
    }
}

// -------------------------------------------------------------------------
// Kernel 4: exact fp32 rescore. 16-lane groups, 4 candidates per wave.
// Packed (d_bits<<32 | code) atomicMin -> lowest-index tie-break.
// -------------------------------------------------------------------------
__global__ __launch_bounds__(256)
void rescore_kernel(const float* __restrict__ X, const float* __restrict__ C,
                    const float* __restrict__ xnorm, const float* __restrict__ cnorm,
                    const unsigned* __restrict__ list, const unsigned* __restrict__ count,
                    unsigned cap, unsigned long long* __restrict__ fin)
{
    const int lane = threadIdx.x & 63;
    const int g16  = lane & 15;
    const int sub  = lane >> 4;
    const int gid  = ((blockIdx.x * 256 + threadIdx.x) >> 6) * 4 + sub;
    const int ng   = ((gridDim.x * 256) >> 6) * 4;
    unsigned n = *count; if (n > cap) n = cap;

    for (unsigned c = gid; c < n; c += ng) {
        const unsigned e = list[c];
        const unsigned tok = e >> 13, code = e & 8191u;
        const float* xr = &X[(size_t)tok * DIMD];
        const float* cr = &C[(size_t)code * DIMD];
        float dot = 0.f;
#pragma unroll
        for (int r = 0; r < 4; ++r) {
            float4 x4 = *(const float4*)&xr[r * 64 + g16 * 4];
            float4 c4 = *(const float4*)&cr[r * 64 + g16 * 4];
            dot = fmaf(x4.x, c4.x, dot);
            dot = fmaf(x4.y, c4.y, dot);
            dot = fmaf(x4.z, c4.z, dot);
            dot = fmaf(x4.w, c4.w, dot);
        }
#pragma unroll
        for (int d = 1; d < 16; d <<= 1) dot += __shfl_xor(dot, d);
        if (g16 == 0) {
            const float dd = xnorm[tok] + cnorm[code] - 2.f * dot;
            const unsigned long long p =
                ((unsigned long long)__float_as_uint(dd) << 32) | code;
            atomicMin(&fin[tok], p);
        }
    }
}

// -------------------------------------------------------------------------
// Kernel 5: gather winner, straight-through output, loss. One atomic/block.
// -------------------------------------------------------------------------
__global__ __launch_bounds__(256)
void finalize_kernel(const float* __restrict__ X, const float* __restrict__ C,
                     const unsigned long long* __restrict__ fin,
                     float* __restrict__ out)
{
    __shared__ float part[4];
    const int lane = threadIdx.x & 63;
    const int wv   = threadIdx.x >> 6;
    const int t0   = blockIdx.x * 64;

    float local = 0.f;
    for (int it = 0; it < 16; ++it) {
        const int t = t0 + wv * 16 + it;
        const unsigned code = (unsigned)(fin[t] & 0xFFFFFFFFull);
        float4 c4 = *(const float4*)&C[(size_t)code * DIMD + lane * 4];
        float4 x4 = *(const float4*)&X[(size_t)t * DIMD + lane * 4];
        float4 w  = {c4.x - x4.x, c4.y - x4.y, c4.z - x4.z, c4.w - x4.w};
        local += w.x * w.x + w.y * w.y + w.z * w.z + w.w * w.w;
        float4 zq = {x4.x + w.x, x4.y + w.y, x4.z + w.z, x4.w + w.w};
        *(float4*)&out[(size_t)t * DIMD + lane * 4] = zq;
        if (lane == 0) out[NELEM + 1 + t] = (float)code;
    }
#pragma unroll
    for (int off = 1; off < 64; off <<= 1) local += __shfl_xor(local, off);
    if (lane == 0) part[wv] = local;
    __syncthreads();
    if (threadIdx.x == 0) {
        const float s = part[0] + part[1] + part[2] + part[3];
        atomicAdd(&out[NELEM], s * (1.25f / (float)NELEM));
    }
}

// -------------------------------------------------------------------------
extern "C" void kernel_launch(void* const* d_in, const int* in_sizes, int n_in,
                              void* d_out, int out_size, void* d_ws, size_t ws_size,
                              hipStream_t stream)
{
    const float* X = (const float*)d_in[0];
    const float* E = (const float*)d_in[1];
    const float* W = (const float*)d_in[2];
    const float* b = (const float*)d_in[3];
    float* out = (float*)d_out;

    char* w = (char*)d_ws;
    float* C            = (float*)w;           w += (size_t)NCODE * DIMD * 4;
    unsigned short* Xb  = (unsigned short*)w;  w += (size_t)NTOK * DIMD * 2;
    unsigned short* Cb2 = (unsigned short*)w;  w += (size_t)NCODE * DIMD * 2;
    float* xnorm        = (float*)w;           w += (size_t)NTOK * 4;
    float* cnorm        = (float*)w;           w += (size_t)NCODE * 4;
    unsigned long long* fin = (unsigned long long*)w; w += (size_t)NTOK * 8;
    unsigned* cnt       = (unsigned*)w;        w += 256;
    unsigned* list      = (unsigned*)w;

    size_t used = (size_t)(w - (char*)d_ws);
    size_t avail = (ws_size > used) ? (ws_size - used) / 4 : 0;
    unsigned cap = (unsigned)((avail > 16777216u) ? 16777216u : avail);

    hipMemsetAsync(cnt, 0, 4, stream);
    hipMemsetAsync(fin, 0xFF, (size_t)NTOK * 8, stream);
    hipMemsetAsync(out + NELEM, 0, 4, stream);

    project_kernel<<<dim3(NCODE / BM, DIMD / BK), 256, 0, stream>>>(E, W, b, C, Cb2);
    convx_kernel<<<NTOK / 4, 256, 0, stream>>>(X, xnorm, Xb);
    cnorm_kernel<<<NCODE / 4, 256, 0, stream>>>(C, cnorm);
    dist_stream_kernel<<<dim3(NTOK / 64, SPLITS_B), 256, 0, stream>>>(
        Xb, Cb2, cnorm, list, cnt, cap);
    rescore_kernel<<<1024, 256, 0, stream>>>(X, C, xnorm, cnorm, list, cnt, cap, fin);
    finalize_kernel<<<NTOK / 64, 256, 0, stream>>>(X, C, fin, out);
}